// Round 13
// baseline (171.437 us; speedup 1.0000x reference)
//
#include <hip/hip_runtime.h>
#include <cstdint>
#include <cstddef>

#define T_TOK 1024
#define H_DIM 1024
#define I_DIM 2816
#define E_NUM 8
#define PAIRS 2048  // T_TOK * top_k(=2)
#define KSPLIT 2    // gemm2 split-K factor (44 BK-iters -> 22 per split)
#define NT1 88      // gemm1 n-tiles (32 gate + 32 up cols each)
#define AMX2_X 32   // 32 x-slots * 4 y = 128 embedded amax2 blocks/expert

typedef __attribute__((ext_vector_type(4))) float f32x4;
typedef __attribute__((ext_vector_type(4))) unsigned int u32x4;
typedef long i64;

// ---------- fp8 e4m3fn encode ----------
__device__ __forceinline__ unsigned char fp8e4m3_sw(float v) {
  v = fminf(448.f, fmaxf(-448.f, v));
  unsigned b = __float_as_uint(v);
  unsigned s = (b >> 24) & 0x80u;
  float a = fabsf(v);
  if (a < 0.015625f) {
    int m = (int)rintf(a * 512.f);
    return (unsigned char)(s | (unsigned)m);
  }
  unsigned ab = b & 0x7fffffffu;
  unsigned rnd = 0x7FFFFu + ((ab >> 20) & 1u);
  ab += rnd;
  int e = (int)(ab >> 23) - 127;
  unsigned m = (ab >> 20) & 7u;
  if (e > 8 || (e == 8 && m > 6)) { e = 8; m = 6; }
  return (unsigned char)(s | (unsigned)((e + 7) << 3) | m);
}

__device__ __forceinline__ unsigned q4(float a, float b, float c, float d) {
#if __has_builtin(__builtin_amdgcn_cvt_pk_fp8_f32)
  unsigned w = (unsigned)__builtin_amdgcn_cvt_pk_fp8_f32(a, b, 0, false);
  return (unsigned)__builtin_amdgcn_cvt_pk_fp8_f32(c, d, (int)w, true);
#else
  return (unsigned)fp8e4m3_sw(a) | ((unsigned)fp8e4m3_sw(b) << 8) |
         ((unsigned)fp8e4m3_sw(c) << 16) | ((unsigned)fp8e4m3_sw(d) << 24);
#endif
}

__device__ __forceinline__ unsigned char q1(float a) {
#if __has_builtin(__builtin_amdgcn_cvt_pk_fp8_f32)
  return (unsigned char)((unsigned)__builtin_amdgcn_cvt_pk_fp8_f32(a, a, 0, false) & 0xFFu);
#else
  return fp8e4m3_sw(a);
#endif
}

__device__ __forceinline__ unsigned q4v(float4 f, float inv) {
  return q4(f.x * inv, f.y * inv, f.z * inv, f.w * inv);
}

__device__ __forceinline__ unsigned q4c(float4 f, float inv) {
  float a = fminf(448.f, fmaxf(-448.f, f.x * inv));
  float b = fminf(448.f, fmaxf(-448.f, f.y * inv));
  float c = fminf(448.f, fmaxf(-448.f, f.z * inv));
  float d = fminf(448.f, fmaxf(-448.f, f.w * inv));
  return q4(a, b, c, d);
}

__device__ __forceinline__ float wave_max(float m) {
#pragma unroll
  for (int off = 32; off > 0; off >>= 1) m = fmaxf(m, __shfl_xor(m, off));
  return m;
}

// top-2 of 8 logits (deterministic; identical code in routing & quant paths)
__device__ __forceinline__ void top2(const float* l, int& i0, int& i1) {
  i0 = 0; float b0 = l[0];
#pragma unroll
  for (int k = 1; k < E_NUM; k++) { if (l[k] > b0) { b0 = l[k]; i0 = k; } }
  i1 = -1; float b1 = -3.4e38f;
#pragma unroll
  for (int k = 0; k < E_NUM; k++) { if (k != i0 && l[k] > b1) { b1 = l[k]; i1 = k; } }
}

// ---------- pre_k: [0,1024) w13 amax partials; 1024 routing; [1025,1537) act quant ----------
__global__ __launch_bounds__(256) void pre_k(const float* __restrict__ w13,
                                             const float* __restrict__ logits,
                                             const float* __restrict__ x,
                                             const float* __restrict__ s13,
                                             float* __restrict__ part13,
                                             int* __restrict__ cnt_g,
                                             int* __restrict__ offs_g,
                                             int* __restrict__ pair_xrow,
                                             float* __restrict__ pair_w,
                                             int* __restrict__ pairidx,
                                             unsigned char* __restrict__ Xq) {
  const int tid = threadIdx.x;
  if (blockIdx.x < 1024) {  // ---- amax13 partial ----
    const int e = blockIdx.x >> 7, sub = blockIdx.x & 127;
    const float4* src = (const float4*)w13 + (size_t)e * (2 * I_DIM * H_DIM / 4);
    int idx = sub * 256 + tid;
    const int stride = 128 * 256;
    float m = 0.f;
#pragma unroll
    for (int j = 0; j < 44; j += 4) {
      float4 v0 = src[idx + (size_t)(j + 0) * stride];
      float4 v1 = src[idx + (size_t)(j + 1) * stride];
      float4 v2 = src[idx + (size_t)(j + 2) * stride];
      float4 v3 = src[idx + (size_t)(j + 3) * stride];
      m = fmaxf(m, fmaxf(fmaxf(fabsf(v0.x), fabsf(v0.y)), fmaxf(fabsf(v0.z), fabsf(v0.w))));
      m = fmaxf(m, fmaxf(fmaxf(fabsf(v1.x), fabsf(v1.y)), fmaxf(fabsf(v1.z), fabsf(v1.w))));
      m = fmaxf(m, fmaxf(fmaxf(fabsf(v2.x), fabsf(v2.y)), fmaxf(fabsf(v2.z), fabsf(v2.w))));
      m = fmaxf(m, fmaxf(fmaxf(fabsf(v3.x), fabsf(v3.y)), fmaxf(fabsf(v3.z), fabsf(v3.w))));
    }
    m = wave_max(m);
    __shared__ float wmax[4];
    int lane = tid & 63, wid = tid >> 6;
    if (lane == 0) wmax[wid] = m;
    __syncthreads();
    if (tid == 0)
      part13[blockIdx.x] = fmaxf(fmaxf(wmax[0], wmax[1]), fmaxf(wmax[2], wmax[3]));
    return;
  }

  if (blockIdx.x == 1024) {  // ---- routing (256 threads x 4 tokens) ----
    __shared__ int cnt_s[E_NUM], pos_s[E_NUM];
    if (tid < E_NUM) cnt_s[tid] = 0;
    __syncthreads();
    int i0s[4], i1s[4];
    float w0s[4], w1s[4];
#pragma unroll
    for (int j = 0; j < 4; j++) {
      int t = tid * 4 + j;
      float l[E_NUM];
#pragma unroll
      for (int k = 0; k < E_NUM; k++) l[k] = logits[t * E_NUM + k];
      int i0, i1;
      top2(l, i0, i1);
      float e1 = expf(l[i1] - l[i0]);
      float d = 1.f + e1;
      i0s[j] = i0; i1s[j] = i1; w0s[j] = 1.f / d; w1s[j] = e1 / d;
      atomicAdd(&cnt_s[i0], 1);
      atomicAdd(&cnt_s[i1], 1);
    }
    __syncthreads();
    if (tid == 0) {
      int s = 0;
#pragma unroll
      for (int e = 0; e < E_NUM; e++) {
        cnt_g[e] = cnt_s[e];
        offs_g[e] = s;
        pos_s[e] = s;
        s += cnt_s[e];
      }
      offs_g[E_NUM] = s;
    }
    __syncthreads();
#pragma unroll
    for (int j = 0; j < 4; j++) {
      int t = tid * 4 + j;
      int s0 = atomicAdd(&pos_s[i0s[j]], 1);
      pair_xrow[s0] = 2 * t; pair_w[s0] = w0s[j]; pairidx[2 * t] = s0;
      int s1 = atomicAdd(&pos_s[i1s[j]], 1);
      pair_xrow[s1] = 2 * t + 1; pair_w[s1] = w1s[j]; pairidx[2 * t + 1] = s1;
    }
    return;
  }

  // ---- activation quant: block handles 2 tokens, token-slot-indexed Xq ----
  {
    const int q = blockIdx.x - 1025;  // 0..511
#pragma unroll
    for (int j = 0; j < 2; j++) {
      int t = q * 2 + j;
      float l[E_NUM];
#pragma unroll
      for (int k = 0; k < E_NUM; k++) l[k] = logits[t * E_NUM + k];
      int i0, i1;
      top2(l, i0, i1);
      float inv0 = 1.f / s13[i0];
      float inv1 = 1.f / s13[i1];
      float4 v = ((const float4*)(x + (size_t)t * H_DIM))[tid];
      ((unsigned*)(Xq + (size_t)(2 * t) * H_DIM))[tid] = q4c(v, inv0);
      ((unsigned*)(Xq + (size_t)(2 * t + 1) * H_DIM))[tid] = q4c(v, inv1);
    }
  }
}

// ---------- GEMM1: BM=128, BN=32g+32u, BK=64, 256 threads, DEPTH-2 prefetch ----------
// coverage invariant: gridDim.y*2*BM = 4*2*128 = 1024 rows >= max expert count.
// blockIdx.x >= 2*NT1: embedded amax2 partials.
__global__ __launch_bounds__(256) void gemm1_k(const float* __restrict__ w13,
                                               const float* __restrict__ w2,
                                               const unsigned char* __restrict__ Xq,
                                               unsigned char* __restrict__ H1,
                                               const int* __restrict__ cnt,
                                               const int* __restrict__ offs,
                                               const float* __restrict__ part13,
                                               float* __restrict__ part2,
                                               const int* __restrict__ pair_xrow,
                                               const float* __restrict__ s13,
                                               const float* __restrict__ s2in) {
  const int e = blockIdx.z;
  const int tid = threadIdx.x, lane = tid & 63, wq = tid >> 6;

  if (blockIdx.x >= 2 * NT1) {  // ---- embedded amax2 partials ----
    const int bx2 = (blockIdx.x - 2 * NT1) * 4 + blockIdx.y;  // 0..127
    const float4* src = (const float4*)w2 + (size_t)e * (H_DIM * I_DIM / 4);
    int idx = bx2 * 256 + tid;
    const int stride = 128 * 256;
    float m = 0.f;
#pragma unroll
    for (int j = 0; j < 22; j++) {
      float4 v = src[idx + (size_t)j * stride];
      m = fmaxf(m, fmaxf(fmaxf(fabsf(v.x), fabsf(v.y)), fmaxf(fabsf(v.z), fabsf(v.w))));
    }
    m = wave_max(m);
    __shared__ float wmax2[4];
    if (lane == 0) wmax2[wq] = m;
    __syncthreads();
    if (tid == 0) {
      float mm = fmaxf(fmaxf(wmax2[0], wmax2[1]), fmaxf(wmax2[2], wmax2[3]));
      part2[e * 128 + bx2] = mm;
    }
    return;
  }

  // ---- reduce part13 -> amax ----
  __shared__ float redA[4];
  {
    float v = part13[e * 128 + (tid & 127)];
    v = wave_max(v);
    if (lane == 0) redA[wq] = v;
  }
  __syncthreads();
  float amax = fmaxf(fmaxf(redA[0], redA[1]), fmaxf(redA[2], redA[3]));

  // sibling decode: ids b, b+8 share nt -> same XCD under round-robin
  const int bid = blockIdx.x;                    // 0..175
  const int nt = (bid & 7) + (bid >> 4) * 8;     // 0..87
  const int mhalf = (bid >> 3) & 1;
  const int m0 = (blockIdx.y * 2 + mhalf) * 128;
  const int count = cnt[e];
  if (m0 >= count) return;
  const int base = offs[e];

  const float inv_w = 448.f / amax;
  const float gs = s13[e] * (amax / 448.f);
  const float inv_a2 = 1.f / s2in[e];

  __shared__ __align__(16) unsigned char As[128][80];
  __shared__ __align__(16) unsigned char Bs[64][80];  // 0..31 gate, 32..63 up

  const int fr = lane & 15, ks = lane >> 4;

  f32x4 accg[2][2], accu[2][2];
#pragma unroll
  for (int i = 0; i < 2; i++)
#pragma unroll
    for (int j = 0; j < 2; j++) { accg[i][j] = (f32x4)0.f; accu[i][j] = (f32x4)0.f; }

  // A staging: 128 rows x 4 segs(16B); thread covers rows ar0 and ar0+64
  const int ar0 = tid >> 2, aseg = tid & 3;
  int pr0 = base + m0 + ar0;      if (pr0 > PAIRS - 1) pr0 = PAIRS - 1;
  int pr1 = base + m0 + ar0 + 64; if (pr1 > PAIRS - 1) pr1 = PAIRS - 1;
  const unsigned char* a0p = Xq + (size_t)pair_xrow[pr0] * H_DIM + aseg * 16;
  const unsigned char* a1p = Xq + (size_t)pair_xrow[pr1] * H_DIM + aseg * 16;

  // B staging: 32 rows x 8 segs(8 f32 -> 8B); thread covers gate row brow + up row brow
  const int brow = tid >> 3, bseg = tid & 7;
  const float* bg_src = w13 + ((size_t)e * 2 * I_DIM + (size_t)nt * 32 + brow) * H_DIM + bseg * 8;
  const float* bu_src = bg_src + (size_t)I_DIM * H_DIM;

  // depth-2 register sets (named; no runtime-indexed arrays)
  u32x4 Aa0 = *(const u32x4*)a0p;
  u32x4 Aa1 = *(const u32x4*)a1p;
  float4 gA0 = ((const float4*)bg_src)[0], gA1 = ((const float4*)bg_src)[1];
  float4 uA0 = ((const float4*)bu_src)[0], uA1 = ((const float4*)bu_src)[1];
  u32x4 Ab0 = *(const u32x4*)(a0p + 64);
  u32x4 Ab1 = *(const u32x4*)(a1p + 64);
  float4 gB0 = ((const float4*)(bg_src + 64))[0], gB1 = ((const float4*)(bg_src + 64))[1];
  float4 uB0 = ((const float4*)(bu_src + 64))[0], uB1 = ((const float4*)(bu_src + 64))[1];
  unsigned qg0 = q4v(gA0, inv_w), qg1 = q4v(gA1, inv_w);
  unsigned qu0 = q4v(uA0, inv_w), qu1 = q4v(uA1, inv_w);

#define MFMA_BLOCK()                                                                     \
  _Pragma("unroll")                                                                      \
  for (int kk = 0; kk < 2; kk++) {                                                       \
    i64 a0 = *(const i64*)&As[wq * 32 + fr][kk * 32 + ks * 8];                           \
    i64 a1 = *(const i64*)&As[wq * 32 + 16 + fr][kk * 32 + ks * 8];                      \
    _Pragma("unroll")                                                                    \
    for (int ni = 0; ni < 2; ni++) {                                                     \
      i64 bg = *(const i64*)&Bs[ni * 16 + fr][kk * 32 + ks * 8];                         \
      i64 bu = *(const i64*)&Bs[32 + ni * 16 + fr][kk * 32 + ks * 8];                    \
      accg[0][ni] = __builtin_amdgcn_mfma_f32_16x16x32_fp8_fp8(a0, bg, accg[0][ni], 0, 0, 0); \
      accg[1][ni] = __builtin_amdgcn_mfma_f32_16x16x32_fp8_fp8(a1, bg, accg[1][ni], 0, 0, 0); \
      accu[0][ni] = __builtin_amdgcn_mfma_f32_16x16x32_fp8_fp8(a0, bu, accu[0][ni], 0, 0, 0); \
      accu[1][ni] = __builtin_amdgcn_mfma_f32_16x16x32_fp8_fp8(a1, bu, accu[1][ni], 0, 0, 0); \
    }                                                                                    \
  }

  for (int t = 0; t < H_DIM / 64; t += 2) {
    // ---- even iter t: data in set A (q holds q(t)) ----
    __syncthreads();
    *(u32x4*)&As[ar0][aseg * 16] = Aa0;
    *(u32x4*)&As[ar0 + 64][aseg * 16] = Aa1;
    ((unsigned*)&Bs[brow][bseg * 8])[0] = qg0;
    ((unsigned*)&Bs[brow][bseg * 8])[1] = qg1;
    ((unsigned*)&Bs[32 + brow][bseg * 8])[0] = qu0;
    ((unsigned*)&Bs[32 + brow][bseg * 8])[1] = qu1;
    __syncthreads();
    if (t + 2 < H_DIM / 64) {  // issue loads for iter t+2 into set A
      int k0 = (t + 2) * 64;
      Aa0 = *(const u32x4*)(a0p + k0);
      Aa1 = *(const u32x4*)(a1p + k0);
      gA0 = ((const float4*)(bg_src + k0))[0]; gA1 = ((const float4*)(bg_src + k0))[1];
      uA0 = ((const float4*)(bu_src + k0))[0]; uA1 = ((const float4*)(bu_src + k0))[1];
    }
    MFMA_BLOCK();
    qg0 = q4v(gB0, inv_w); qg1 = q4v(gB1, inv_w);  // q(t+1) from set B
    qu0 = q4v(uB0, inv_w); qu1 = q4v(uB1, inv_w);

    // ---- odd iter t+1: data in set B ----
    __syncthreads();
    *(u32x4*)&As[ar0][aseg * 16] = Ab0;
    *(u32x4*)&As[ar0 + 64][aseg * 16] = Ab1;
    ((unsigned*)&Bs[brow][bseg * 8])[0] = qg0;
    ((unsigned*)&Bs[brow][bseg * 8])[1] = qg1;
    ((unsigned*)&Bs[32 + brow][bseg * 8])[0] = qu0;
    ((unsigned*)&Bs[32 + brow][bseg * 8])[1] = qu1;
    __syncthreads();
    if (t + 3 < H_DIM / 64) {  // issue loads for iter t+3 into set B
      int k0 = (t + 3) * 64;
      Ab0 = *(const u32x4*)(a0p + k0);
      Ab1 = *(const u32x4*)(a1p + k0);
      gB0 = ((const float4*)(bg_src + k0))[0]; gB1 = ((const float4*)(bg_src + k0))[1];
      uB0 = ((const float4*)(bu_src + k0))[0]; uB1 = ((const float4*)(bu_src + k0))[1];
    }
    MFMA_BLOCK();
    if (t + 2 < H_DIM / 64) {  // q(t+2) from set A (loaded one sub-iter ago)
      qg0 = q4v(gA0, inv_w); qg1 = q4v(gA1, inv_w);
      qu0 = q4v(uA0, inv_w); qu1 = q4v(uA1, inv_w);
    }
  }
#undef MFMA_BLOCK

  const int rg = lane >> 4;
#pragma unroll
  for (int mi = 0; mi < 2; mi++) {
#pragma unroll
    for (int rr = 0; rr < 4; rr++) {
      int lrow = wq * 32 + mi * 16 + rg * 4 + rr;
      if (m0 + lrow < count) {
        size_t p = (size_t)(base + m0 + lrow);
#pragma unroll
        for (int ni = 0; ni < 2; ni++) {
          int col = nt * 32 + ni * 16 + fr;
          float g = accg[mi][ni][rr] * gs;
          float u = accu[mi][ni][rr] * gs;
          float act = g / (1.f + expf(-g)) * u * inv_a2;
          act = fminf(448.f, fmaxf(-448.f, act));
          H1[p * I_DIM + col] = q1(act);
        }
      }
    }
  }
}

// ---------- GEMM2: split-K=2, BM=64, BN=64, BK=64, 256 threads ----------
// coverage invariant: gridDim.y*BM = 8*64 = 512 rows >= max expert count.
__global__ __launch_bounds__(256) void gemm2_k(const float* __restrict__ w2,
                                               const unsigned char* __restrict__ H1,
                                               float* __restrict__ Op,
                                               const int* __restrict__ cnt,
                                               const int* __restrict__ offs,
                                               const float* __restrict__ part2,
                                               const float* __restrict__ s2in,
                                               const float* __restrict__ pair_w) {
  const int e = blockIdx.z;
  const int tid = threadIdx.x, lane = tid & 63, wq = tid >> 6;

  // reduce part2 -> amax
  __shared__ float redA[4];
  {
    float v = part2[e * 128 + (tid & 127)];
    v = wave_max(v);
    if (lane == 0) redA[wq] = v;
  }
  __syncthreads();
  float amax = fmaxf(fmaxf(redA[0], redA[1]), fmaxf(redA[2], redA[3]));

  const int count = cnt[e];
  const int m0 = blockIdx.y * 64;
  if (m0 >= count) return;
  const int nt = blockIdx.x & 15;
  const int ksp = blockIdx.x >> 4;
  const int n0 = nt * 64;
  const int base = offs[e];

  const float inv_w = 448.f / amax;
  const float s2 = s2in[e] * (amax / 448.f);

  __shared__ __align__(16) unsigned char As[64][80];
  __shared__ __align__(16) unsigned char Bs[64][80];

  const int fr = lane & 15, ks = lane >> 4;

  f32x4 acc[4];
#pragma unroll
  for (int i = 0; i < 4; i++) acc[i] = (f32x4)0.f;

  const int KITER = (I_DIM / 64) / KSPLIT;  // 22
  const int kbase = ksp * KITER * 64;

  // A: 64 rows x 4 segs(16B) = 256 slots
  const int arow = tid >> 2, aseg = tid & 3;
  int pr = base + m0 + arow; if (pr > PAIRS - 1) pr = PAIRS - 1;
  const unsigned char* a_src = H1 + (size_t)pr * I_DIM + kbase + aseg * 16;

  // B: thread covers rows brow and brow+32; 8 segs of 8 f32
  const int brow = tid >> 3, bseg = tid & 7;
  const float* b0_src = w2 + ((size_t)e * H_DIM + n0 + brow) * I_DIM + kbase + bseg * 8;
  const float* b1_src = b0_src + (size_t)32 * I_DIM;

  u32x4 ra = *(const u32x4*)a_src;
  float4 f00 = ((const float4*)b0_src)[0], f01 = ((const float4*)b0_src)[1];
  float4 f10 = ((const float4*)b1_src)[0], f11 = ((const float4*)b1_src)[1];
  unsigned q00 = q4v(f00, inv_w), q01 = q4v(f01, inv_w);
  unsigned q10 = q4v(f10, inv_w), q11 = q4v(f11, inv_w);

  for (int t = 0; t < KITER; ++t) {
    __syncthreads();
    *(u32x4*)&As[arow][aseg * 16] = ra;
    ((unsigned*)&Bs[brow][bseg * 8])[0] = q00;
    ((unsigned*)&Bs[brow][bseg * 8])[1] = q01;
    ((unsigned*)&Bs[brow + 32][bseg * 8])[0] = q10;
    ((unsigned*)&Bs[brow + 32][bseg * 8])[1] = q11;
    __syncthreads();
    if (t + 1 < KITER) {
      int k0 = (t + 1) * 64;
      ra = *(const u32x4*)(a_src + k0);
      f00 = ((const float4*)(b0_src + k0))[0]; f01 = ((const float4*)(b0_src + k0))[1];
      f10 = ((const float4*)(b1_src + k0))[0]; f11 = ((const float4*)(b1_src + k0))[1];
    }
#pragma unroll
    for (int kk = 0; kk < 2; kk++) {
      i64 a0 = *(const i64*)&As[wq * 16 + fr][kk * 32 + ks * 8];
#pragma unroll
      for (int ni = 0; ni < 4; ni++) {
        i64 b = *(const i64*)&Bs[ni * 16 + fr][kk * 32 + ks * 8];
        acc[ni] = __builtin_amdgcn_mfma_f32_16x16x32_fp8_fp8(a0, b, acc[ni], 0, 0, 0);
      }
    }
    q00 = q4v(f00, inv_w); q01 = q4v(f01, inv_w);  // quant after MFMA (vmcnt covered)
    q10 = q4v(f10, inv_w); q11 = q4v(f11, inv_w);
  }

  const int rg = lane >> 4;
#pragma unroll
  for (int rr = 0; rr < 4; rr++) {
    int lrow = wq * 16 + rg * 4 + rr;
    if (m0 + lrow < count) {
      size_t p = (size_t)(base + m0 + lrow);
      float pw = pair_w[p];
#pragma unroll
      for (int ni = 0; ni < 4; ni++) {
        int col = n0 + ni * 16 + fr;
        Op[((size_t)ksp * PAIRS + p) * H_DIM + col] = acc[ni][rr] * s2 * pw;
      }
    }
  }
}

// ---------- combine: out[t,:] = sum over 2 pairs x KSPLIT partials (fixed order) ----------
__global__ __launch_bounds__(256) void combine_k(const float* __restrict__ Op,
                                                 const int* __restrict__ pairidx,
                                                 float* __restrict__ out) {
  int t = blockIdx.x;
  int p0 = pairidx[2 * t], p1 = pairidx[2 * t + 1];
  f32x4 acc = (f32x4)0.f;
#pragma unroll
  for (int s = 0; s < KSPLIT; s++) {
    f32x4 a = ((const f32x4*)(Op + ((size_t)s * PAIRS + p0) * H_DIM))[threadIdx.x];
    f32x4 b = ((const f32x4*)(Op + ((size_t)s * PAIRS + p1) * H_DIM))[threadIdx.x];
    acc += a + b;
  }
  ((f32x4*)(out + (size_t)t * H_DIM))[threadIdx.x] = acc;
}

extern "C" void kernel_launch(void* const* d_in, const int* in_sizes, int n_in,
                              void* d_out, int out_size, void* d_ws, size_t ws_size,
                              hipStream_t stream) {
  (void)in_sizes; (void)n_in; (void)out_size; (void)ws_size;
  const float* x      = (const float*)d_in[0];
  const float* logits = (const float*)d_in[1];
  const float* w13    = (const float*)d_in[2];
  const float* w2     = (const float*)d_in[3];
  const float* s13    = (const float*)d_in[4];
  const float* s2in   = (const float*)d_in[5];
  float* out = (float*)d_out;

  char* ws = (char*)d_ws;
  int* cnt       = (int*)(ws + 128);
  int* offs      = (int*)(ws + 192);
  float* part13  = (float*)(ws + 4096);   // 1024 floats
  float* part2   = (float*)(ws + 8192);   // 1024 floats
  int* pair_xrow = (int*)(ws + 17408);
  float* pair_w  = (float*)(ws + 25600);
  int* pairidx   = (int*)(ws + 33792);
  unsigned char* Xq = (unsigned char*)(ws + (size_t)(1 << 20));        // 2 MB
  unsigned char* H1 = (unsigned char*)(ws + (size_t)4 * (1 << 20));    // 5.77 MB
  float* Op         = (float*)(ws + (size_t)10 * (1 << 20));           // KSPLIT*8 MB

  // amax13 partials + routing + activation quant in ONE launch
  pre_k<<<1537, 256, 0, stream>>>(w13, logits, x, s13, part13, cnt, offs,
                                  pair_xrow, pair_w, pairidx, Xq);

  // gemm1 (1408 active, depth-2 pipeline) + embedded amax2 partials
  gemm1_k<<<dim3(2 * NT1 + AMX2_X, 4, E_NUM), 256, 0, stream>>>(
      w13, w2, Xq, H1, cnt, offs, part13, part2, pair_xrow, s13, s2in);

  // y=8 x BM=64 = 512-row coverage (fixes R12's 256-row under-coverage)
  gemm2_k<<<dim3(16 * KSPLIT, 8, E_NUM), 256, 0, stream>>>(
      w2, H1, Op, cnt, offs, part2, s2in, pair_w);

  combine_k<<<T_TOK, 256, 0, stream>>>(Op, pairidx, out);
}

// Round 14
// 164.836 us; speedup vs baseline: 1.0400x; 1.0400x over previous
//
#include <hip/hip_runtime.h>
#include <cstdint>
#include <cstddef>

#define T_TOK 1024
#define H_DIM 1024
#define I_DIM 2816
#define E_NUM 8
#define PAIRS 2048  // T_TOK * top_k(=2)
#define KSPLIT 4    // gemm2 split-K factor (44 BK-iters -> 11 per split)
#define NT1 88      // gemm1 n-tiles (32 gate + 32 up cols each)
#define AMX2_X 32   // 32 x-slots * 4 y = 128 embedded amax2 blocks/expert

typedef __attribute__((ext_vector_type(4))) float f32x4;
typedef __attribute__((ext_vector_type(4))) unsigned int u32x4;
typedef long i64;

// ---------- fp8 e4m3fn encode ----------
__device__ __forceinline__ unsigned char fp8e4m3_sw(float v) {
  v = fminf(448.f, fmaxf(-448.f, v));
  unsigned b = __float_as_uint(v);
  unsigned s = (b >> 24) & 0x80u;
  float a = fabsf(v);
  if (a < 0.015625f) {
    int m = (int)rintf(a * 512.f);
    return (unsigned char)(s | (unsigned)m);
  }
  unsigned ab = b & 0x7fffffffu;
  unsigned rnd = 0x7FFFFu + ((ab >> 20) & 1u);
  ab += rnd;
  int e = (int)(ab >> 23) - 127;
  unsigned m = (ab >> 20) & 7u;
  if (e > 8 || (e == 8 && m > 6)) { e = 8; m = 6; }
  return (unsigned char)(s | (unsigned)((e + 7) << 3) | m);
}

__device__ __forceinline__ unsigned q4(float a, float b, float c, float d) {
#if __has_builtin(__builtin_amdgcn_cvt_pk_fp8_f32)
  unsigned w = (unsigned)__builtin_amdgcn_cvt_pk_fp8_f32(a, b, 0, false);
  return (unsigned)__builtin_amdgcn_cvt_pk_fp8_f32(c, d, (int)w, true);
#else
  return (unsigned)fp8e4m3_sw(a) | ((unsigned)fp8e4m3_sw(b) << 8) |
         ((unsigned)fp8e4m3_sw(c) << 16) | ((unsigned)fp8e4m3_sw(d) << 24);
#endif
}

__device__ __forceinline__ unsigned char q1(float a) {
#if __has_builtin(__builtin_amdgcn_cvt_pk_fp8_f32)
  return (unsigned char)((unsigned)__builtin_amdgcn_cvt_pk_fp8_f32(a, a, 0, false) & 0xFFu);
#else
  return fp8e4m3_sw(a);
#endif
}

__device__ __forceinline__ unsigned q4v(float4 f, float inv) {
  return q4(f.x * inv, f.y * inv, f.z * inv, f.w * inv);
}

__device__ __forceinline__ unsigned q4c(float4 f, float inv) {
  float a = fminf(448.f, fmaxf(-448.f, f.x * inv));
  float b = fminf(448.f, fmaxf(-448.f, f.y * inv));
  float c = fminf(448.f, fmaxf(-448.f, f.z * inv));
  float d = fminf(448.f, fmaxf(-448.f, f.w * inv));
  return q4(a, b, c, d);
}

__device__ __forceinline__ float wave_max(float m) {
#pragma unroll
  for (int off = 32; off > 0; off >>= 1) m = fmaxf(m, __shfl_xor(m, off));
  return m;
}

// top-2 of 8 logits (deterministic; identical code in routing & quant paths)
__device__ __forceinline__ void top2(const float* l, int& i0, int& i1) {
  i0 = 0; float b0 = l[0];
#pragma unroll
  for (int k = 1; k < E_NUM; k++) { if (l[k] > b0) { b0 = l[k]; i0 = k; } }
  i1 = -1; float b1 = -3.4e38f;
#pragma unroll
  for (int k = 0; k < E_NUM; k++) { if (k != i0 && l[k] > b1) { b1 = l[k]; i1 = k; } }
}

// ---------- pre_k: [0,1024) w13 amax partials; 1024 routing; [1025,1537) act quant ----------
__global__ __launch_bounds__(256) void pre_k(const float* __restrict__ w13,
                                             const float* __restrict__ logits,
                                             const float* __restrict__ x,
                                             const float* __restrict__ s13,
                                             float* __restrict__ part13,
                                             int* __restrict__ cnt_g,
                                             int* __restrict__ offs_g,
                                             int* __restrict__ pair_xrow,
                                             float* __restrict__ pair_w,
                                             int* __restrict__ pairidx,
                                             unsigned char* __restrict__ Xq) {
  const int tid = threadIdx.x;
  if (blockIdx.x < 1024) {  // ---- amax13 partial ----
    const int e = blockIdx.x >> 7, sub = blockIdx.x & 127;
    const float4* src = (const float4*)w13 + (size_t)e * (2 * I_DIM * H_DIM / 4);
    int idx = sub * 256 + tid;
    const int stride = 128 * 256;
    float m = 0.f;
#pragma unroll
    for (int j = 0; j < 44; j += 4) {
      float4 v0 = src[idx + (size_t)(j + 0) * stride];
      float4 v1 = src[idx + (size_t)(j + 1) * stride];
      float4 v2 = src[idx + (size_t)(j + 2) * stride];
      float4 v3 = src[idx + (size_t)(j + 3) * stride];
      m = fmaxf(m, fmaxf(fmaxf(fabsf(v0.x), fabsf(v0.y)), fmaxf(fabsf(v0.z), fabsf(v0.w))));
      m = fmaxf(m, fmaxf(fmaxf(fabsf(v1.x), fabsf(v1.y)), fmaxf(fabsf(v1.z), fabsf(v1.w))));
      m = fmaxf(m, fmaxf(fmaxf(fabsf(v2.x), fabsf(v2.y)), fmaxf(fabsf(v2.z), fabsf(v2.w))));
      m = fmaxf(m, fmaxf(fmaxf(fabsf(v3.x), fabsf(v3.y)), fmaxf(fabsf(v3.z), fabsf(v3.w))));
    }
    m = wave_max(m);
    __shared__ float wmax[4];
    int lane = tid & 63, wid = tid >> 6;
    if (lane == 0) wmax[wid] = m;
    __syncthreads();
    if (tid == 0)
      part13[blockIdx.x] = fmaxf(fmaxf(wmax[0], wmax[1]), fmaxf(wmax[2], wmax[3]));
    return;
  }

  if (blockIdx.x == 1024) {  // ---- routing (256 threads x 4 tokens) ----
    __shared__ int cnt_s[E_NUM], pos_s[E_NUM];
    if (tid < E_NUM) cnt_s[tid] = 0;
    __syncthreads();
    int i0s[4], i1s[4];
    float w0s[4], w1s[4];
#pragma unroll
    for (int j = 0; j < 4; j++) {
      int t = tid * 4 + j;
      float l[E_NUM];
#pragma unroll
      for (int k = 0; k < E_NUM; k++) l[k] = logits[t * E_NUM + k];
      int i0, i1;
      top2(l, i0, i1);
      float e1 = expf(l[i1] - l[i0]);
      float d = 1.f + e1;
      i0s[j] = i0; i1s[j] = i1; w0s[j] = 1.f / d; w1s[j] = e1 / d;
      atomicAdd(&cnt_s[i0], 1);
      atomicAdd(&cnt_s[i1], 1);
    }
    __syncthreads();
    if (tid == 0) {
      int s = 0;
#pragma unroll
      for (int e = 0; e < E_NUM; e++) {
        cnt_g[e] = cnt_s[e];
        offs_g[e] = s;
        pos_s[e] = s;
        s += cnt_s[e];
      }
      offs_g[E_NUM] = s;
    }
    __syncthreads();
#pragma unroll
    for (int j = 0; j < 4; j++) {
      int t = tid * 4 + j;
      int s0 = atomicAdd(&pos_s[i0s[j]], 1);
      pair_xrow[s0] = 2 * t; pair_w[s0] = w0s[j]; pairidx[2 * t] = s0;
      int s1 = atomicAdd(&pos_s[i1s[j]], 1);
      pair_xrow[s1] = 2 * t + 1; pair_w[s1] = w1s[j]; pairidx[2 * t + 1] = s1;
    }
    return;
  }

  // ---- activation quant: block handles 2 tokens, token-slot-indexed Xq ----
  {
    const int q = blockIdx.x - 1025;  // 0..511
#pragma unroll
    for (int j = 0; j < 2; j++) {
      int t = q * 2 + j;
      float l[E_NUM];
#pragma unroll
      for (int k = 0; k < E_NUM; k++) l[k] = logits[t * E_NUM + k];
      int i0, i1;
      top2(l, i0, i1);
      float inv0 = 1.f / s13[i0];
      float inv1 = 1.f / s13[i1];
      float4 v = ((const float4*)(x + (size_t)t * H_DIM))[tid];
      ((unsigned*)(Xq + (size_t)(2 * t) * H_DIM))[tid] = q4c(v, inv0);
      ((unsigned*)(Xq + (size_t)(2 * t + 1) * H_DIM))[tid] = q4c(v, inv1);
    }
  }
}

// ---------- GEMM1: R8 form. BM=256, BN=32g+32u, BK=64, 512 threads, depth-1 ----------
// coverage invariant: gridDim.y * BM = 4 * 256 = 1024 rows >= max expert count.
// blockIdx.x >= NT1: embedded amax2 partial blocks (plain stores to part2).
__global__ __launch_bounds__(512) void gemm1_k(const float* __restrict__ w13,
                                               const float* __restrict__ w2,
                                               const unsigned char* __restrict__ Xq,
                                               unsigned char* __restrict__ H1,
                                               const int* __restrict__ cnt,
                                               const int* __restrict__ offs,
                                               const float* __restrict__ part13,
                                               float* __restrict__ part2,
                                               const int* __restrict__ pair_xrow,
                                               const float* __restrict__ s13,
                                               const float* __restrict__ s2in) {
  const int e = blockIdx.z;
  const int tid = threadIdx.x, lane = tid & 63, wq = tid >> 6;

  if (blockIdx.x >= NT1) {  // ---- embedded amax2 partials ----
    const int bx2 = (blockIdx.x - NT1) * 4 + blockIdx.y;  // 0..127
    const float4* src = (const float4*)w2 + (size_t)e * (H_DIM * I_DIM / 4);
    int idx = bx2 * 512 + tid;
    const int stride = 128 * 512;
    float m = 0.f;
#pragma unroll
    for (int j = 0; j < 11; j++) {
      float4 v = src[idx + (size_t)j * stride];
      m = fmaxf(m, fmaxf(fmaxf(fabsf(v.x), fabsf(v.y)), fmaxf(fabsf(v.z), fabsf(v.w))));
    }
    m = wave_max(m);
    __shared__ float wmax2[8];
    if (lane == 0) wmax2[wq] = m;
    __syncthreads();
    if (tid == 0) {
      float mm = wmax2[0];
#pragma unroll
      for (int j = 1; j < 8; j++) mm = fmaxf(mm, wmax2[j]);
      part2[e * 128 + bx2] = mm;
    }
    return;
  }

  // ---- reduce part13 -> amax ----
  __shared__ float redA[8];
  {
    float v = part13[e * 128 + (tid & 127)];
    v = wave_max(v);
    if (lane == 0) redA[wq] = v;
  }
  __syncthreads();
  float amax = redA[0];
#pragma unroll
  for (int j = 1; j < 8; j++) amax = fmaxf(amax, redA[j]);

  const int count = cnt[e];
  const int m0 = blockIdx.y * 256;
  if (m0 >= count) return;
  const int nt = blockIdx.x;
  const int base = offs[e];

  const float inv_w = 448.f / amax;
  const float gs = s13[e] * (amax / 448.f);
  const float inv_a2 = 1.f / s2in[e];

  __shared__ __align__(16) unsigned char As[256][80];
  __shared__ __align__(16) unsigned char Bs[64][80];  // rows 0..31 gate, 32..63 up

  const int fr = lane & 15, ks = lane >> 4;

  f32x4 accg[2][2], accu[2][2];
#pragma unroll
  for (int i = 0; i < 2; i++)
#pragma unroll
    for (int j = 0; j < 2; j++) { accg[i][j] = (f32x4)0.f; accu[i][j] = (f32x4)0.f; }

  // A staging: 256 rows x 4 segs(16B) = 1024 slots; thread covers rows ar0, ar0+128
  const int ar0 = tid >> 2, aseg = tid & 3;
  int pr0 = base + m0 + ar0;       if (pr0 > PAIRS - 1) pr0 = PAIRS - 1;
  int pr1 = base + m0 + ar0 + 128; if (pr1 > PAIRS - 1) pr1 = PAIRS - 1;
  const unsigned char* a_src0 = Xq + (size_t)pair_xrow[pr0] * H_DIM + aseg * 16;
  const unsigned char* a_src1 = Xq + (size_t)pair_xrow[pr1] * H_DIM + aseg * 16;

  // B staging: 64 rows x 8 segs(8 f32 -> 8B fp8); rows 0..31 gate, 32..63 up
  const int brow = tid >> 3, bseg = tid & 7;
  const size_t brg = (size_t)nt * 32 + (brow & 31) + (size_t)(brow >> 5) * I_DIM;
  const float* b_src = w13 + ((size_t)e * 2 * I_DIM + brg) * H_DIM + bseg * 8;

  u32x4 ra0 = *(const u32x4*)a_src0;
  u32x4 ra1 = *(const u32x4*)a_src1;
  float4 fb0 = ((const float4*)b_src)[0], fb1 = ((const float4*)b_src)[1];
  unsigned qb0 = q4v(fb0, inv_w), qb1 = q4v(fb1, inv_w);

  for (int t = 0; t < H_DIM / 64; ++t) {
    __syncthreads();
    *(u32x4*)&As[ar0][aseg * 16] = ra0;
    *(u32x4*)&As[ar0 + 128][aseg * 16] = ra1;
    ((unsigned*)&Bs[brow][bseg * 8])[0] = qb0;
    ((unsigned*)&Bs[brow][bseg * 8])[1] = qb1;
    __syncthreads();
    if (t + 1 < H_DIM / 64) {  // issue raw loads; quantize after MFMA
      int k0 = (t + 1) * 64;
      ra0 = *(const u32x4*)(a_src0 + k0);
      ra1 = *(const u32x4*)(a_src1 + k0);
      fb0 = ((const float4*)(b_src + k0))[0];
      fb1 = ((const float4*)(b_src + k0))[1];
    }
#pragma unroll
    for (int kk = 0; kk < 2; kk++) {
      i64 a0 = *(const i64*)&As[wq * 32 + fr][kk * 32 + ks * 8];
      i64 a1 = *(const i64*)&As[wq * 32 + 16 + fr][kk * 32 + ks * 8];
#pragma unroll
      for (int ni = 0; ni < 2; ni++) {
        i64 bg = *(const i64*)&Bs[ni * 16 + fr][kk * 32 + ks * 8];
        i64 bu = *(const i64*)&Bs[32 + ni * 16 + fr][kk * 32 + ks * 8];
        accg[0][ni] = __builtin_amdgcn_mfma_f32_16x16x32_fp8_fp8(a0, bg, accg[0][ni], 0, 0, 0);
        accg[1][ni] = __builtin_amdgcn_mfma_f32_16x16x32_fp8_fp8(a1, bg, accg[1][ni], 0, 0, 0);
        accu[0][ni] = __builtin_amdgcn_mfma_f32_16x16x32_fp8_fp8(a0, bu, accu[0][ni], 0, 0, 0);
        accu[1][ni] = __builtin_amdgcn_mfma_f32_16x16x32_fp8_fp8(a1, bu, accu[1][ni], 0, 0, 0);
      }
    }
    qb0 = q4v(fb0, inv_w);  // vmcnt wait lands here, after MFMA block
    qb1 = q4v(fb1, inv_w);
  }

  const int rg = lane >> 4;
#pragma unroll
  for (int mi = 0; mi < 2; mi++) {
#pragma unroll
    for (int rr = 0; rr < 4; rr++) {
      int lrow = wq * 32 + mi * 16 + rg * 4 + rr;
      if (m0 + lrow < count) {
        size_t p = (size_t)(base + m0 + lrow);
#pragma unroll
        for (int ni = 0; ni < 2; ni++) {
          int col = nt * 32 + ni * 16 + fr;
          float g = accg[mi][ni][rr] * gs;
          float u = accu[mi][ni][rr] * gs;
          float act = g / (1.f + expf(-g)) * u * inv_a2;
          act = fminf(448.f, fmaxf(-448.f, act));
          H1[p * I_DIM + col] = q1(act);
        }
      }
    }
  }
}

// ---------- GEMM2: R8 form. split-K=4, BM=128, BN=64, BK=64, 512 threads ----------
// coverage invariant: gridDim.y * BM = 8 * 128 = 1024 rows >= max expert count.
__global__ __launch_bounds__(512) void gemm2_k(const float* __restrict__ w2,
                                               const unsigned char* __restrict__ H1,
                                               float* __restrict__ Op,
                                               const int* __restrict__ cnt,
                                               const int* __restrict__ offs,
                                               const float* __restrict__ part2,
                                               const float* __restrict__ s2in,
                                               const float* __restrict__ pair_w) {
  const int e = blockIdx.z;
  const int tid = threadIdx.x, lane = tid & 63, wq = tid >> 6;

  // reduce part2 -> amax
  __shared__ float redA[8];
  {
    float v = part2[e * 128 + (tid & 127)];
    v = wave_max(v);
    if (lane == 0) redA[wq] = v;
  }
  __syncthreads();
  float amax = redA[0];
#pragma unroll
  for (int j = 1; j < 8; j++) amax = fmaxf(amax, redA[j]);

  const int count = cnt[e];
  const int m0 = blockIdx.y * 128;
  if (m0 >= count) return;
  const int nt = blockIdx.x & 15;
  const int ksp = blockIdx.x >> 4;
  const int n0 = nt * 64;
  const int base = offs[e];

  const float inv_w = 448.f / amax;
  const float s2 = s2in[e] * (amax / 448.f);

  __shared__ __align__(16) unsigned char As[128][80];
  __shared__ __align__(16) unsigned char Bs[64][80];

  const int fr = lane & 15, ks = lane >> 4;

  f32x4 acc[4];
#pragma unroll
  for (int i = 0; i < 4; i++) acc[i] = (f32x4)0.f;

  const int arow = tid >> 2, aseg = tid & 3;
  int pr = base + m0 + arow; if (pr > PAIRS - 1) pr = PAIRS - 1;
  const unsigned char* a_src = H1 + (size_t)pr * I_DIM + aseg * 16;

  const int brow = tid >> 3, bseg = tid & 7;
  const float* b_src = w2 + ((size_t)e * H_DIM + n0 + brow) * I_DIM + bseg * 8;

  const int KITER = (I_DIM / 64) / KSPLIT;  // 11
  const int kbase = ksp * KITER * 64;

  u32x4 ra = *(const u32x4*)(a_src + kbase);
  float4 fb0 = ((const float4*)(b_src + kbase))[0];
  float4 fb1 = ((const float4*)(b_src + kbase))[1];
  unsigned qb0 = q4v(fb0, inv_w), qb1 = q4v(fb1, inv_w);

  for (int t = 0; t < KITER; ++t) {
    __syncthreads();
    *(u32x4*)&As[arow][aseg * 16] = ra;
    ((unsigned*)&Bs[brow][bseg * 8])[0] = qb0;
    ((unsigned*)&Bs[brow][bseg * 8])[1] = qb1;
    __syncthreads();
    if (t + 1 < KITER) {
      int k0 = kbase + (t + 1) * 64;
      ra = *(const u32x4*)(a_src + k0);
      fb0 = ((const float4*)(b_src + k0))[0];
      fb1 = ((const float4*)(b_src + k0))[1];
    }
#pragma unroll
    for (int kk = 0; kk < 2; kk++) {
      i64 a0 = *(const i64*)&As[wq * 16 + fr][kk * 32 + ks * 8];
#pragma unroll
      for (int ni = 0; ni < 4; ni++) {
        i64 b = *(const i64*)&Bs[ni * 16 + fr][kk * 32 + ks * 8];
        acc[ni] = __builtin_amdgcn_mfma_f32_16x16x32_fp8_fp8(a0, b, acc[ni], 0, 0, 0);
      }
    }
    qb0 = q4v(fb0, inv_w);  // vmcnt wait after MFMA block
    qb1 = q4v(fb1, inv_w);
  }

  const int rg = lane >> 4;
#pragma unroll
  for (int rr = 0; rr < 4; rr++) {
    int lrow = wq * 16 + rg * 4 + rr;
    if (m0 + lrow < count) {
      size_t p = (size_t)(base + m0 + lrow);
      float pw = pair_w[p];
#pragma unroll
      for (int ni = 0; ni < 4; ni++) {
        int col = n0 + ni * 16 + fr;
        Op[((size_t)ksp * PAIRS + p) * H_DIM + col] = acc[ni][rr] * s2 * pw;
      }
    }
  }
}

// ---------- combine: out[t,:] = sum over 2 pairs x KSPLIT partials (fixed order) ----------
__global__ __launch_bounds__(256) void combine_k(const float* __restrict__ Op,
                                                 const int* __restrict__ pairidx,
                                                 float* __restrict__ out) {
  int t = blockIdx.x;
  int p0 = pairidx[2 * t], p1 = pairidx[2 * t + 1];
  f32x4 acc = (f32x4)0.f;
#pragma unroll
  for (int s = 0; s < KSPLIT; s++) {
    f32x4 a = ((const f32x4*)(Op + ((size_t)s * PAIRS + p0) * H_DIM))[threadIdx.x];
    f32x4 b = ((const f32x4*)(Op + ((size_t)s * PAIRS + p1) * H_DIM))[threadIdx.x];
    acc += a + b;
  }
  ((f32x4*)(out + (size_t)t * H_DIM))[threadIdx.x] = acc;
}

extern "C" void kernel_launch(void* const* d_in, const int* in_sizes, int n_in,
                              void* d_out, int out_size, void* d_ws, size_t ws_size,
                              hipStream_t stream) {
  (void)in_sizes; (void)n_in; (void)out_size; (void)ws_size;
  const float* x      = (const float*)d_in[0];
  const float* logits = (const float*)d_in[1];
  const float* w13    = (const float*)d_in[2];
  const float* w2     = (const float*)d_in[3];
  const float* s13    = (const float*)d_in[4];
  const float* s2in   = (const float*)d_in[5];
  float* out = (float*)d_out;

  char* ws = (char*)d_ws;
  int* cnt       = (int*)(ws + 128);
  int* offs      = (int*)(ws + 192);
  float* part13  = (float*)(ws + 4096);   // 1024 floats
  float* part2   = (float*)(ws + 8192);   // 1024 floats
  int* pair_xrow = (int*)(ws + 17408);
  float* pair_w  = (float*)(ws + 25600);
  int* pairidx   = (int*)(ws + 33792);
  unsigned char* Xq = (unsigned char*)(ws + (size_t)(1 << 20));        // 2 MB
  unsigned char* H1 = (unsigned char*)(ws + (size_t)4 * (1 << 20));    // 5.77 MB
  float* Op         = (float*)(ws + (size_t)10 * (1 << 20));           // KSPLIT*8 MB

  // amax13 partials + routing + activation quant in ONE launch
  pre_k<<<1537, 256, 0, stream>>>(w13, logits, x, s13, part13, cnt, offs,
                                  pair_xrow, pair_w, pairidx, Xq);

  // gemm1 (R8 form, 512 threads) + embedded amax2 partials (warms LLC with w2)
  gemm1_k<<<dim3(NT1 + AMX2_X, 4, E_NUM), 512, 0, stream>>>(
      w13, w2, Xq, H1, cnt, offs, part13, part2, pair_xrow, s13, s2in);

  // R8 form: KSPLIT=4, BM=128, y=8 -> 1024-row coverage
  gemm2_k<<<dim3(16 * KSPLIT, 8, E_NUM), 512, 0, stream>>>(
      w2, H1, Op, cnt, offs, part2, s2in, pair_w);

  combine_k<<<T_TOK, 256, 0, stream>>>(Op, pairidx, out);
}

// Round 15
// 163.350 us; speedup vs baseline: 1.0495x; 1.0091x over previous
//
#include <hip/hip_runtime.h>
#include <cstdint>
#include <cstddef>

#define T_TOK 1024
#define H_DIM 1024
#define I_DIM 2816
#define E_NUM 8
#define PAIRS 2048  // T_TOK * top_k(=2)
#define KSPLIT 4    // gemm2 split-K factor (44 BK-iters -> 11 per split)
#define NT1 88      // gemm1 n-tiles (32 gate + 32 up cols each)
#define AMX2_X 32   // 32 x-slots * 4 y = 128 embedded amax2 blocks/expert

typedef __attribute__((ext_vector_type(4))) float f32x4;
typedef __attribute__((ext_vector_type(4))) unsigned int u32x4;
typedef long i64;

// ---------- fp8 e4m3fn encode ----------
__device__ __forceinline__ unsigned char fp8e4m3_sw(float v) {
  v = fminf(448.f, fmaxf(-448.f, v));
  unsigned b = __float_as_uint(v);
  unsigned s = (b >> 24) & 0x80u;
  float a = fabsf(v);
  if (a < 0.015625f) {
    int m = (int)rintf(a * 512.f);
    return (unsigned char)(s | (unsigned)m);
  }
  unsigned ab = b & 0x7fffffffu;
  unsigned rnd = 0x7FFFFu + ((ab >> 20) & 1u);
  ab += rnd;
  int e = (int)(ab >> 23) - 127;
  unsigned m = (ab >> 20) & 7u;
  if (e > 8 || (e == 8 && m > 6)) { e = 8; m = 6; }
  return (unsigned char)(s | (unsigned)((e + 7) << 3) | m);
}

__device__ __forceinline__ unsigned q4(float a, float b, float c, float d) {
#if __has_builtin(__builtin_amdgcn_cvt_pk_fp8_f32)
  unsigned w = (unsigned)__builtin_amdgcn_cvt_pk_fp8_f32(a, b, 0, false);
  return (unsigned)__builtin_amdgcn_cvt_pk_fp8_f32(c, d, (int)w, true);
#else
  return (unsigned)fp8e4m3_sw(a) | ((unsigned)fp8e4m3_sw(b) << 8) |
         ((unsigned)fp8e4m3_sw(c) << 16) | ((unsigned)fp8e4m3_sw(d) << 24);
#endif
}

__device__ __forceinline__ unsigned char q1(float a) {
#if __has_builtin(__builtin_amdgcn_cvt_pk_fp8_f32)
  return (unsigned char)((unsigned)__builtin_amdgcn_cvt_pk_fp8_f32(a, a, 0, false) & 0xFFu);
#else
  return fp8e4m3_sw(a);
#endif
}

__device__ __forceinline__ unsigned q4v(float4 f, float inv) {
  return q4(f.x * inv, f.y * inv, f.z * inv, f.w * inv);
}

__device__ __forceinline__ unsigned q4c(float4 f, float inv) {
  float a = fminf(448.f, fmaxf(-448.f, f.x * inv));
  float b = fminf(448.f, fmaxf(-448.f, f.y * inv));
  float c = fminf(448.f, fmaxf(-448.f, f.z * inv));
  float d = fminf(448.f, fmaxf(-448.f, f.w * inv));
  return q4(a, b, c, d);
}

__device__ __forceinline__ float wave_max(float m) {
#pragma unroll
  for (int off = 32; off > 0; off >>= 1) m = fmaxf(m, __shfl_xor(m, off));
  return m;
}

// top-2 of 8 logits (deterministic; identical code in routing & quant paths)
__device__ __forceinline__ void top2(const float* l, int& i0, int& i1) {
  i0 = 0; float b0 = l[0];
#pragma unroll
  for (int k = 1; k < E_NUM; k++) { if (l[k] > b0) { b0 = l[k]; i0 = k; } }
  i1 = -1; float b1 = -3.4e38f;
#pragma unroll
  for (int k = 0; k < E_NUM; k++) { if (k != i0 && l[k] > b1) { b1 = l[k]; i1 = k; } }
}

// ---------- pre_k: [0,1024) w13 amax partials; 1024 routing; [1025,1537) act quant ----------
__global__ __launch_bounds__(256) void pre_k(const float* __restrict__ w13,
                                             const float* __restrict__ logits,
                                             const float* __restrict__ x,
                                             const float* __restrict__ s13,
                                             float* __restrict__ part13,
                                             int* __restrict__ cnt_g,
                                             int* __restrict__ offs_g,
                                             int* __restrict__ pair_xrow,
                                             float* __restrict__ pair_w,
                                             int* __restrict__ pairidx,
                                             unsigned char* __restrict__ Xq) {
  const int tid = threadIdx.x;
  if (blockIdx.x < 1024) {  // ---- amax13 partial ----
    const int e = blockIdx.x >> 7, sub = blockIdx.x & 127;
    const float4* src = (const float4*)w13 + (size_t)e * (2 * I_DIM * H_DIM / 4);
    int idx = sub * 256 + tid;
    const int stride = 128 * 256;
    float m = 0.f;
#pragma unroll
    for (int j = 0; j < 44; j += 4) {
      float4 v0 = src[idx + (size_t)(j + 0) * stride];
      float4 v1 = src[idx + (size_t)(j + 1) * stride];
      float4 v2 = src[idx + (size_t)(j + 2) * stride];
      float4 v3 = src[idx + (size_t)(j + 3) * stride];
      m = fmaxf(m, fmaxf(fmaxf(fabsf(v0.x), fabsf(v0.y)), fmaxf(fabsf(v0.z), fabsf(v0.w))));
      m = fmaxf(m, fmaxf(fmaxf(fabsf(v1.x), fabsf(v1.y)), fmaxf(fabsf(v1.z), fabsf(v1.w))));
      m = fmaxf(m, fmaxf(fmaxf(fabsf(v2.x), fabsf(v2.y)), fmaxf(fabsf(v2.z), fabsf(v2.w))));
      m = fmaxf(m, fmaxf(fmaxf(fabsf(v3.x), fabsf(v3.y)), fmaxf(fabsf(v3.z), fabsf(v3.w))));
    }
    m = wave_max(m);
    __shared__ float wmax[4];
    int lane = tid & 63, wid = tid >> 6;
    if (lane == 0) wmax[wid] = m;
    __syncthreads();
    if (tid == 0)
      part13[blockIdx.x] = fmaxf(fmaxf(wmax[0], wmax[1]), fmaxf(wmax[2], wmax[3]));
    return;
  }

  if (blockIdx.x == 1024) {  // ---- routing (256 threads x 4 tokens) ----
    __shared__ int cnt_s[E_NUM], pos_s[E_NUM];
    if (tid < E_NUM) cnt_s[tid] = 0;
    __syncthreads();
    int i0s[4], i1s[4];
    float w0s[4], w1s[4];
#pragma unroll
    for (int j = 0; j < 4; j++) {
      int t = tid * 4 + j;
      float l[E_NUM];
#pragma unroll
      for (int k = 0; k < E_NUM; k++) l[k] = logits[t * E_NUM + k];
      int i0, i1;
      top2(l, i0, i1);
      float e1 = expf(l[i1] - l[i0]);
      float d = 1.f + e1;
      i0s[j] = i0; i1s[j] = i1; w0s[j] = 1.f / d; w1s[j] = e1 / d;
      atomicAdd(&cnt_s[i0], 1);
      atomicAdd(&cnt_s[i1], 1);
    }
    __syncthreads();
    if (tid == 0) {
      int s = 0;
#pragma unroll
      for (int e = 0; e < E_NUM; e++) {
        cnt_g[e] = cnt_s[e];
        offs_g[e] = s;
        pos_s[e] = s;
        s += cnt_s[e];
      }
      offs_g[E_NUM] = s;
    }
    __syncthreads();
#pragma unroll
    for (int j = 0; j < 4; j++) {
      int t = tid * 4 + j;
      int s0 = atomicAdd(&pos_s[i0s[j]], 1);
      pair_xrow[s0] = 2 * t; pair_w[s0] = w0s[j]; pairidx[2 * t] = s0;
      int s1 = atomicAdd(&pos_s[i1s[j]], 1);
      pair_xrow[s1] = 2 * t + 1; pair_w[s1] = w1s[j]; pairidx[2 * t + 1] = s1;
    }
    return;
  }

  // ---- activation quant: block handles 2 tokens, token-slot-indexed Xq ----
  {
    const int q = blockIdx.x - 1025;  // 0..511
#pragma unroll
    for (int j = 0; j < 2; j++) {
      int t = q * 2 + j;
      float l[E_NUM];
#pragma unroll
      for (int k = 0; k < E_NUM; k++) l[k] = logits[t * E_NUM + k];
      int i0, i1;
      top2(l, i0, i1);
      float inv0 = 1.f / s13[i0];
      float inv1 = 1.f / s13[i1];
      float4 v = ((const float4*)(x + (size_t)t * H_DIM))[tid];
      ((unsigned*)(Xq + (size_t)(2 * t) * H_DIM))[tid] = q4c(v, inv0);
      ((unsigned*)(Xq + (size_t)(2 * t + 1) * H_DIM))[tid] = q4c(v, inv1);
    }
  }
}

// ---------- GEMM1: BM=256, BN=32g+32u, BK=64, 512 threads, DOUBLE-BUFFERED LDS ----------
// one barrier per K-iter (write buf[c^1] while computing buf[c]).
// coverage invariant: gridDim.y * BM = 4 * 256 = 1024 rows >= max expert count.
// blockIdx.x >= NT1: embedded amax2 partial blocks (plain stores to part2).
__global__ __launch_bounds__(512) void gemm1_k(const float* __restrict__ w13,
                                               const float* __restrict__ w2,
                                               const unsigned char* __restrict__ Xq,
                                               unsigned char* __restrict__ H1,
                                               const int* __restrict__ cnt,
                                               const int* __restrict__ offs,
                                               const float* __restrict__ part13,
                                               float* __restrict__ part2,
                                               const int* __restrict__ pair_xrow,
                                               const float* __restrict__ s13,
                                               const float* __restrict__ s2in) {
  const int e = blockIdx.z;
  const int tid = threadIdx.x, lane = tid & 63, wq = tid >> 6;

  if (blockIdx.x >= NT1) {  // ---- embedded amax2 partials ----
    const int bx2 = (blockIdx.x - NT1) * 4 + blockIdx.y;  // 0..127
    const float4* src = (const float4*)w2 + (size_t)e * (H_DIM * I_DIM / 4);
    int idx = bx2 * 512 + tid;
    const int stride = 128 * 512;
    float m = 0.f;
#pragma unroll
    for (int j = 0; j < 11; j++) {
      float4 v = src[idx + (size_t)j * stride];
      m = fmaxf(m, fmaxf(fmaxf(fabsf(v.x), fabsf(v.y)), fmaxf(fabsf(v.z), fabsf(v.w))));
    }
    m = wave_max(m);
    __shared__ float wmax2[8];
    if (lane == 0) wmax2[wq] = m;
    __syncthreads();
    if (tid == 0) {
      float mm = wmax2[0];
#pragma unroll
      for (int j = 1; j < 8; j++) mm = fmaxf(mm, wmax2[j]);
      part2[e * 128 + bx2] = mm;
    }
    return;
  }

  // ---- reduce part13 -> amax ----
  __shared__ float redA[8];
  {
    float v = part13[e * 128 + (tid & 127)];
    v = wave_max(v);
    if (lane == 0) redA[wq] = v;
  }
  __syncthreads();
  float amax = redA[0];
#pragma unroll
  for (int j = 1; j < 8; j++) amax = fmaxf(amax, redA[j]);

  const int count = cnt[e];
  const int m0 = blockIdx.y * 256;
  if (m0 >= count) return;
  const int nt = blockIdx.x;
  const int base = offs[e];

  const float inv_w = 448.f / amax;
  const float gs = s13[e] * (amax / 448.f);
  const float inv_a2 = 1.f / s2in[e];

  __shared__ __align__(16) unsigned char As[2][256][80];
  __shared__ __align__(16) unsigned char Bs[2][64][80];  // rows 0..31 gate, 32..63 up

  const int fr = lane & 15, ks = lane >> 4;

  f32x4 accg[2][2], accu[2][2];
#pragma unroll
  for (int i = 0; i < 2; i++)
#pragma unroll
    for (int j = 0; j < 2; j++) { accg[i][j] = (f32x4)0.f; accu[i][j] = (f32x4)0.f; }

  // A staging: 256 rows x 4 segs(16B) = 1024 slots; thread covers rows ar0, ar0+128
  const int ar0 = tid >> 2, aseg = tid & 3;
  int pr0 = base + m0 + ar0;       if (pr0 > PAIRS - 1) pr0 = PAIRS - 1;
  int pr1 = base + m0 + ar0 + 128; if (pr1 > PAIRS - 1) pr1 = PAIRS - 1;
  const unsigned char* a_src0 = Xq + (size_t)pair_xrow[pr0] * H_DIM + aseg * 16;
  const unsigned char* a_src1 = Xq + (size_t)pair_xrow[pr1] * H_DIM + aseg * 16;

  // B staging: 64 rows x 8 segs(8 f32 -> 8B fp8); rows 0..31 gate, 32..63 up
  const int brow = tid >> 3, bseg = tid & 7;
  const size_t brg = (size_t)nt * 32 + (brow & 31) + (size_t)(brow >> 5) * I_DIM;
  const float* b_src = w13 + ((size_t)e * 2 * I_DIM + brg) * H_DIM + bseg * 8;

  const int NIT = H_DIM / 64;  // 16

  // prologue: stage tile 0 into buf 0; load+quant tile 1 into regs
  u32x4 ra0 = *(const u32x4*)a_src0;
  u32x4 ra1 = *(const u32x4*)a_src1;
  float4 fb0 = ((const float4*)b_src)[0], fb1 = ((const float4*)b_src)[1];
  {
    unsigned q0 = q4v(fb0, inv_w), q1_ = q4v(fb1, inv_w);
    *(u32x4*)&As[0][ar0][aseg * 16] = ra0;
    *(u32x4*)&As[0][ar0 + 128][aseg * 16] = ra1;
    ((unsigned*)&Bs[0][brow][bseg * 8])[0] = q0;
    ((unsigned*)&Bs[0][brow][bseg * 8])[1] = q1_;
  }
  ra0 = *(const u32x4*)(a_src0 + 64);
  ra1 = *(const u32x4*)(a_src1 + 64);
  fb0 = ((const float4*)(b_src + 64))[0];
  fb1 = ((const float4*)(b_src + 64))[1];
  unsigned qb0 = q4v(fb0, inv_w), qb1 = q4v(fb1, inv_w);
  __syncthreads();

  int c = 0;
  for (int t = 0; t < NIT; ++t) {
    if (t + 1 < NIT) {  // write tile t+1 into buf c^1 (last read of that buf ended at t-1's barrier)
      *(u32x4*)&As[c ^ 1][ar0][aseg * 16] = ra0;
      *(u32x4*)&As[c ^ 1][ar0 + 128][aseg * 16] = ra1;
      ((unsigned*)&Bs[c ^ 1][brow][bseg * 8])[0] = qb0;
      ((unsigned*)&Bs[c ^ 1][brow][bseg * 8])[1] = qb1;
    }
    if (t + 2 < NIT) {  // issue raw loads for tile t+2
      int k0 = (t + 2) * 64;
      ra0 = *(const u32x4*)(a_src0 + k0);
      ra1 = *(const u32x4*)(a_src1 + k0);
      fb0 = ((const float4*)(b_src + k0))[0];
      fb1 = ((const float4*)(b_src + k0))[1];
    }
#pragma unroll
    for (int kk = 0; kk < 2; kk++) {
      i64 a0 = *(const i64*)&As[c][wq * 32 + fr][kk * 32 + ks * 8];
      i64 a1 = *(const i64*)&As[c][wq * 32 + 16 + fr][kk * 32 + ks * 8];
#pragma unroll
      for (int ni = 0; ni < 2; ni++) {
        i64 bg = *(const i64*)&Bs[c][ni * 16 + fr][kk * 32 + ks * 8];
        i64 bu = *(const i64*)&Bs[c][32 + ni * 16 + fr][kk * 32 + ks * 8];
        accg[0][ni] = __builtin_amdgcn_mfma_f32_16x16x32_fp8_fp8(a0, bg, accg[0][ni], 0, 0, 0);
        accg[1][ni] = __builtin_amdgcn_mfma_f32_16x16x32_fp8_fp8(a1, bg, accg[1][ni], 0, 0, 0);
        accu[0][ni] = __builtin_amdgcn_mfma_f32_16x16x32_fp8_fp8(a0, bu, accu[0][ni], 0, 0, 0);
        accu[1][ni] = __builtin_amdgcn_mfma_f32_16x16x32_fp8_fp8(a1, bu, accu[1][ni], 0, 0, 0);
      }
    }
    if (t + 2 < NIT) {  // quantize t+2 after MFMA (vmcnt wait covered)
      qb0 = q4v(fb0, inv_w);
      qb1 = q4v(fb1, inv_w);
    }
    __syncthreads();  // ONE barrier per iter
    c ^= 1;
  }

  const int rg = lane >> 4;
#pragma unroll
  for (int mi = 0; mi < 2; mi++) {
#pragma unroll
    for (int rr = 0; rr < 4; rr++) {
      int lrow = wq * 32 + mi * 16 + rg * 4 + rr;
      if (m0 + lrow < count) {
        size_t p = (size_t)(base + m0 + lrow);
#pragma unroll
        for (int ni = 0; ni < 2; ni++) {
          int col = nt * 32 + ni * 16 + fr;
          float g = accg[mi][ni][rr] * gs;
          float u = accu[mi][ni][rr] * gs;
          float act = g / (1.f + expf(-g)) * u * inv_a2;
          act = fminf(448.f, fmaxf(-448.f, act));
          H1[p * I_DIM + col] = q1(act);
        }
      }
    }
  }
}

// ---------- GEMM2: split-K=4, BM=128, BN=64, BK=64, 512 threads, DOUBLE-BUFFERED LDS ----------
// coverage invariant: gridDim.y * BM = 8 * 128 = 1024 rows >= max expert count.
__global__ __launch_bounds__(512) void gemm2_k(const float* __restrict__ w2,
                                               const unsigned char* __restrict__ H1,
                                               float* __restrict__ Op,
                                               const int* __restrict__ cnt,
                                               const int* __restrict__ offs,
                                               const float* __restrict__ part2,
                                               const float* __restrict__ s2in,
                                               const float* __restrict__ pair_w) {
  const int e = blockIdx.z;
  const int tid = threadIdx.x, lane = tid & 63, wq = tid >> 6;

  // reduce part2 -> amax
  __shared__ float redA[8];
  {
    float v = part2[e * 128 + (tid & 127)];
    v = wave_max(v);
    if (lane == 0) redA[wq] = v;
  }
  __syncthreads();
  float amax = redA[0];
#pragma unroll
  for (int j = 1; j < 8; j++) amax = fmaxf(amax, redA[j]);

  const int count = cnt[e];
  const int m0 = blockIdx.y * 128;
  if (m0 >= count) return;
  const int nt = blockIdx.x & 15;
  const int ksp = blockIdx.x >> 4;
  const int n0 = nt * 64;
  const int base = offs[e];

  const float inv_w = 448.f / amax;
  const float s2 = s2in[e] * (amax / 448.f);

  __shared__ __align__(16) unsigned char As[2][128][80];
  __shared__ __align__(16) unsigned char Bs[2][64][80];

  const int fr = lane & 15, ks = lane >> 4;

  f32x4 acc[4];
#pragma unroll
  for (int i = 0; i < 4; i++) acc[i] = (f32x4)0.f;

  const int arow = tid >> 2, aseg = tid & 3;
  int pr = base + m0 + arow; if (pr > PAIRS - 1) pr = PAIRS - 1;
  const unsigned char* a_src = H1 + (size_t)pr * I_DIM + aseg * 16;

  const int brow = tid >> 3, bseg = tid & 7;
  const float* b_src = w2 + ((size_t)e * H_DIM + n0 + brow) * I_DIM + bseg * 8;

  const int KITER = (I_DIM / 64) / KSPLIT;  // 11
  const int kbase = ksp * KITER * 64;

  // prologue: stage tile 0 into buf 0; load+quant tile 1 into regs
  u32x4 ra = *(const u32x4*)(a_src + kbase);
  float4 fb0 = ((const float4*)(b_src + kbase))[0];
  float4 fb1 = ((const float4*)(b_src + kbase))[1];
  {
    unsigned q0 = q4v(fb0, inv_w), q1_ = q4v(fb1, inv_w);
    *(u32x4*)&As[0][arow][aseg * 16] = ra;
    ((unsigned*)&Bs[0][brow][bseg * 8])[0] = q0;
    ((unsigned*)&Bs[0][brow][bseg * 8])[1] = q1_;
  }
  ra = *(const u32x4*)(a_src + kbase + 64);
  fb0 = ((const float4*)(b_src + kbase + 64))[0];
  fb1 = ((const float4*)(b_src + kbase + 64))[1];
  unsigned qb0 = q4v(fb0, inv_w), qb1 = q4v(fb1, inv_w);
  __syncthreads();

  int c = 0;
  for (int t = 0; t < KITER; ++t) {
    if (t + 1 < KITER) {
      *(u32x4*)&As[c ^ 1][arow][aseg * 16] = ra;
      ((unsigned*)&Bs[c ^ 1][brow][bseg * 8])[0] = qb0;
      ((unsigned*)&Bs[c ^ 1][brow][bseg * 8])[1] = qb1;
    }
    if (t + 2 < KITER) {
      int k0 = kbase + (t + 2) * 64;
      ra = *(const u32x4*)(a_src + k0);
      fb0 = ((const float4*)(b_src + k0))[0];
      fb1 = ((const float4*)(b_src + k0))[1];
    }
#pragma unroll
    for (int kk = 0; kk < 2; kk++) {
      i64 a0 = *(const i64*)&As[c][wq * 16 + fr][kk * 32 + ks * 8];
#pragma unroll
      for (int ni = 0; ni < 4; ni++) {
        i64 b = *(const i64*)&Bs[c][ni * 16 + fr][kk * 32 + ks * 8];
        acc[ni] = __builtin_amdgcn_mfma_f32_16x16x32_fp8_fp8(a0, b, acc[ni], 0, 0, 0);
      }
    }
    if (t + 2 < KITER) {
      qb0 = q4v(fb0, inv_w);
      qb1 = q4v(fb1, inv_w);
    }
    __syncthreads();  // ONE barrier per iter
    c ^= 1;
  }

  const int rg = lane >> 4;
#pragma unroll
  for (int rr = 0; rr < 4; rr++) {
    int lrow = wq * 16 + rg * 4 + rr;
    if (m0 + lrow < count) {
      size_t p = (size_t)(base + m0 + lrow);
      float pw = pair_w[p];
#pragma unroll
      for (int ni = 0; ni < 4; ni++) {
        int col = n0 + ni * 16 + fr;
        Op[((size_t)ksp * PAIRS + p) * H_DIM + col] = acc[ni][rr] * s2 * pw;
      }
    }
  }
}

// ---------- combine: out[t,:] = sum over 2 pairs x KSPLIT partials (fixed order) ----------
__global__ __launch_bounds__(256) void combine_k(const float* __restrict__ Op,
                                                 const int* __restrict__ pairidx,
                                                 float* __restrict__ out) {
  int t = blockIdx.x;
  int p0 = pairidx[2 * t], p1 = pairidx[2 * t + 1];
  f32x4 acc = (f32x4)0.f;
#pragma unroll
  for (int s = 0; s < KSPLIT; s++) {
    f32x4 a = ((const f32x4*)(Op + ((size_t)s * PAIRS + p0) * H_DIM))[threadIdx.x];
    f32x4 b = ((const f32x4*)(Op + ((size_t)s * PAIRS + p1) * H_DIM))[threadIdx.x];
    acc += a + b;
  }
  ((f32x4*)(out + (size_t)t * H_DIM))[threadIdx.x] = acc;
}

extern "C" void kernel_launch(void* const* d_in, const int* in_sizes, int n_in,
                              void* d_out, int out_size, void* d_ws, size_t ws_size,
                              hipStream_t stream) {
  (void)in_sizes; (void)n_in; (void)out_size; (void)ws_size;
  const float* x      = (const float*)d_in[0];
  const float* logits = (const float*)d_in[1];
  const float* w13    = (const float*)d_in[2];
  const float* w2     = (const float*)d_in[3];
  const float* s13    = (const float*)d_in[4];
  const float* s2in   = (const float*)d_in[5];
  float* out = (float*)d_out;

  char* ws = (char*)d_ws;
  int* cnt       = (int*)(ws + 128);
  int* offs      = (int*)(ws + 192);
  float* part13  = (float*)(ws + 4096);   // 1024 floats
  float* part2   = (float*)(ws + 8192);   // 1024 floats
  int* pair_xrow = (int*)(ws + 17408);
  float* pair_w  = (float*)(ws + 25600);
  int* pairidx   = (int*)(ws + 33792);
  unsigned char* Xq = (unsigned char*)(ws + (size_t)(1 << 20));        // 2 MB
  unsigned char* H1 = (unsigned char*)(ws + (size_t)4 * (1 << 20));    // 5.77 MB
  float* Op         = (float*)(ws + (size_t)10 * (1 << 20));           // KSPLIT*8 MB

  // amax13 partials + routing + activation quant in ONE launch
  pre_k<<<1537, 256, 0, stream>>>(w13, logits, x, s13, part13, cnt, offs,
                                  pair_xrow, pair_w, pairidx, Xq);

  // gemm1 (R8 form + LDS double-buffer) + embedded amax2 partials
  gemm1_k<<<dim3(NT1 + AMX2_X, 4, E_NUM), 512, 0, stream>>>(
      w13, w2, Xq, H1, cnt, offs, part13, part2, pair_xrow, s13, s2in);

  // KSPLIT=4, BM=128, y=8 -> 1024-row coverage, LDS double-buffer
  gemm2_k<<<dim3(16 * KSPLIT, 8, E_NUM), 512, 0, stream>>>(
      w2, H1, Op, cnt, offs, part2, s2in, pair_w);

  combine_k<<<T_TOK, 256, 0, stream>>>(Op, pairidx, out);
}